// Round 3
// baseline (10750.063 us; speedup 1.0000x reference)
//
#include <hip/hip_runtime.h>
#include <stdint.h>
#include <stddef.h>

#define BB   4096
#define KTOT 544
#define AROW 1088            /* KTOT*2 bytes per A-matrix row */
#define NSL  17
#define SM1  255

/* workspace layout (bytes) */
#define WS_A0   0
#define WS_A1   4456448                   /* 4096*1088 */
#define WS_WT   8912896                   /* 2 A buffers */
#define WS_WCMT (WS_WT + 1114112)         /* 8*128*544*2 */
#define WS_CNT  (WS_WCMT + 16384)
#define WS_TOT  (WS_CNT + 2048)

typedef __attribute__((ext_vector_type(8))) short short8;
typedef __attribute__((ext_vector_type(4))) float floatx4;

#define MFMA(a, b, c) __builtin_amdgcn_mfma_f32_16x16x32_bf16((a), (b), (c), 0, 0, 0)

static __device__ __forceinline__ uint16_t f2b(float f) {
  union { float f; uint32_t u; } v; v.f = f;
  return (uint16_t)((v.u + 0x7FFFu + ((v.u >> 16) & 1u)) >> 16);  /* RNE */
}
static __device__ __forceinline__ uint32_t pack2(float a, float b) {
  return (uint32_t)f2b(a) | ((uint32_t)f2b(b) << 16);
}
static __device__ __forceinline__ float b2f(uint16_t h) {
  union { uint32_t u; float f; } v; v.u = ((uint32_t)h) << 16; return v.f;
}
static __device__ __forceinline__ float sigm(float x) { return 1.0f / (1.0f + __expf(-x)); }
static __device__ __forceinline__ float tanh_(float x) {
  float a = fabsf(x);
  float e = __expf(-2.0f * a);
  float t = (1.0f - e) / (1.0f + e);
  return copysignf(t, x);
}

/* Repack combined weight [K=544][1024] (f32 in) -> bf16, per-colchunk, transposed,
   col-interleaved: tile col n (0..127): gate=n>>5, n5=n&31, hcol = gate*256 + cb*32
   + ((n5&15)<<1) + (n5>>4). K rows: 0..255 = W_h_p, 256..511 = W_s_p,
   512..531 = W_x_p, rest zero. Head weights [Wc|Wm] -> bf16 [32 cols][256 k]. */
__global__ void prep_kernel(const float* __restrict__ Whp, const float* __restrict__ Wsp,
                            const float* __restrict__ Wxp, const float* __restrict__ Wc,
                            const float* __restrict__ Wm, uint16_t* __restrict__ Wt,
                            uint16_t* __restrict__ Wcmt) {
  int tid = blockIdx.x * 256 + threadIdx.x;
  const int NW = 8 * 128 * KTOT;
  if (tid < NW) {
    int k = tid % KTOT;
    int n = (tid / KTOT) & 127;
    int cb = tid / (KTOT * 128);
    int gate = n >> 5;
    int n5 = n & 31;
    int col = gate * 256 + cb * 32 + ((n5 & 15) << 1) + (n5 >> 4);
    float v = 0.0f;
    if (k < 256) v = Whp[k * 1024 + col];
    else if (k < 512) v = Wsp[(k - 256) * 1024 + col];
    else if (k < 532) v = Wxp[(k - 512) * 1024 + col];
    Wt[tid] = f2b(v);
  } else if (tid < NW + 8192) {
    int i2 = tid - NW;
    int k = i2 & 255;
    int n = i2 >> 8;
    float v = 0.0f;
    if (n < 3) v = Wc[k * 3 + n];
    else if (n < 25) v = Wm[k * 22 + (n - 3)];
    Wcmt[i2] = f2b(v);
  }
}

__global__ __launch_bounds__(256, 1) void scan_kernel(
    const float* __restrict__ val, const float* __restrict__ delta,
    const float* __restrict__ Wd, const float* __restrict__ bd,
    const float* __restrict__ Wxt, const float* __restrict__ Wdt,
    const float* __restrict__ bt, const float* __restrict__ Wxs,
    const float* __restrict__ bs, const float* __restrict__ bp,
    const float* __restrict__ bc, const float* __restrict__ bm,
    const uint8_t* __restrict__ Wt, const uint8_t* __restrict__ Wcm,
    uint8_t* __restrict__ Abuf0, uint8_t* __restrict__ Abuf1,
    uint32_t* __restrict__ counters, float* __restrict__ outp) {
  /* transient pool: GEMM A double-buffer (2x8K) / gate-exchange (4x8K) /
     extras staging x|demb|hs1 (3x8K) / head stage (2.1K) */
  __shared__ __align__(16) uint8_t pool[32768];
  __shared__ __align__(16) uint8_t ldsT[8192];        /* T gate, [128][32] bf16, persists extras->gates */
  __shared__ __align__(16) uint16_t wext[5][1024];    /* Wdt | Wxt | Wxs_i | Wxs_o | Wxs_g tiles [32n][32k] */
  __shared__ float wdbd[64];                          /* W_d(32) | b_d(32) */
  __shared__ float bcm[32];                           /* bc(3) | bm(22) | 0 */

  const int tid = threadIdx.x;
  const int wv = tid >> 6;
  const int ln = tid & 63;
  const int quad = ln >> 4;
  const int l16 = ln & 15;
  const int rb = blockIdx.x & 31;   /* row group: 128 batch rows; 8 sibling wgs */
  const int cb = blockIdx.x >> 5;   /* h-column chunk: 32 h cols (x4 gates) */
  const int grow0 = rb * 128;
  uint32_t* cnt = counters + rb * 16;
  float* out_cat = outp;
  float* out_val = outp + (size_t)SM1 * BB * 3;

  /* ---- startup: small weights into LDS (f32 -> bf16) ---- */
  {
    int n_e = tid >> 3;
    int k0 = (tid & 7) << 2;
    int colD = cb * 32 + ((n_e & 15) << 1) + (n_e >> 4);
#pragma unroll
    for (int j = 0; j < 4; ++j) {
      int k = k0 + j;
      wext[0][n_e * 32 + k] = f2b(Wdt[k * 256 + colD]);
      wext[1][n_e * 32 + k] = (k < 20) ? f2b(Wxt[k * 256 + colD]) : (uint16_t)0;
      wext[2][n_e * 32 + k] = (k < 20) ? f2b(Wxs[k * 1024 + colD]) : (uint16_t)0;
      wext[3][n_e * 32 + k] = (k < 20) ? f2b(Wxs[k * 1024 + 512 + colD]) : (uint16_t)0;
      wext[4][n_e * 32 + k] = (k < 20) ? f2b(Wxs[k * 1024 + 768 + colD]) : (uint16_t)0;
    }
    if (tid < 32) wdbd[tid] = Wd[tid];
    else if (tid < 64) wdbd[tid] = bd[tid - 32];
    if (tid >= 64 && tid < 96) {
      int n = tid - 64;
      bcm[n] = (n < 3) ? bc[n] : ((n < 25) ? bm[n - 3] : 0.0f);
    }
  }

  /* per-lane biases (col = cb*32 + l16*2 + nt, gate = wv for main), f32 direct */
  float bpr[2], btr[2], bsir[2], bsor[2], bsgr[2];
#pragma unroll
  for (int nt = 0; nt < 2; ++nt) {
    int c = cb * 32 + l16 * 2 + nt;
    bpr[nt] = bp[wv * 256 + c];
    btr[nt] = bt[c];
    bsir[nt] = bs[c];
    bsor[nt] = bs[512 + c];
    bsgr[nt] = bs[768 + c];
  }

  /* main-GEMM B fragments: resident in VGPRs for all 255 steps */
  short8 Bf[NSL][2];
  {
    const uint8_t* wb = Wt + (size_t)cb * 128 * KTOT * 2;
#pragma unroll
    for (int s = 0; s < NSL; ++s)
#pragma unroll
      for (int nt = 0; nt < 2; ++nt) {
        int n = wv * 32 + nt * 16 + l16;
        Bf[s][nt] = *(const short8*)(wb + (size_t)n * AROW + s * 64 + quad * 16);
      }
  }

  float c_reg[16];
#pragma unroll
  for (int j = 0; j < 16; ++j) c_reg[j] = 0.0f;
  const floatx4 fz = {0.0f, 0.0f, 0.0f, 0.0f};

  __syncthreads();

  /* extras(u): stage x_u (f32->bf16), demb_u; MFMA shared path + time gate;
     write T->ldsT, hs1 (+x pad if cb==0) -> A buffer for step u. */
  auto extras = [&](int u, uint8_t* An) {
    {
      int r = tid >> 1, half = tid & 1;
      int grow = grow0 + r;
      const float2* v2 = (const float2*)(val + ((size_t)u * BB + grow) * 20 + half * 10);
      uint32_t* xr = (uint32_t*)(pool + r * 64);
#pragma unroll
      for (int j = 0; j < 5; ++j) {
        float2 tv = v2[j];
        xr[half * 5 + j] = pack2(tv.x, tv.y);
      }
      if (half) {
#pragma unroll
        for (int j = 10; j < 16; ++j) xr[j] = 0u;
      }
      float d = delta[(size_t)u * BB + grow];
      uint32_t* dr = (uint32_t*)(pool + 8192 + r * 64);
      int e0 = half * 16;
#pragma unroll
      for (int e = 0; e < 16; e += 2) {
        float d0 = tanh_(d * wdbd[e0 + e] + wdbd[32 + e0 + e]);
        float d1 = tanh_(d * wdbd[e0 + e + 1] + wdbd[32 + e0 + e + 1]);
        dr[(e0 + e) >> 1] = pack2(d0, d1);
      }
    }
    __syncthreads();
#pragma unroll
    for (int tt = 0; tt < 2; ++tt) {
      int tm = wv * 2 + tt;
      short8 ax = *(const short8*)(pool + (tm * 16 + l16) * 64 + quad * 16);
      short8 ad = *(const short8*)(pool + 8192 + (tm * 16 + l16) * 64 + quad * 16);
      floatx4 td[2], tp[2], gi[2], go[2], gg[2];
#pragma unroll
      for (int nt = 0; nt < 2; ++nt) {
        td[nt] = fz; tp[nt] = fz; gi[nt] = fz; go[nt] = fz; gg[nt] = fz;
        const uint8_t* wb = (const uint8_t*)wext;
        int fo = (nt * 16 + l16) * 64 + quad * 16;
        short8 b;
        b = *(const short8*)(wb + fo);          td[nt] = MFMA(ad, b, td[nt]);
        b = *(const short8*)(wb + 2048 + fo);   tp[nt] = MFMA(ax, b, tp[nt]);
        b = *(const short8*)(wb + 4096 + fo);   gi[nt] = MFMA(ax, b, gi[nt]);
        b = *(const short8*)(wb + 6144 + fo);   go[nt] = MFMA(ax, b, go[nt]);
        b = *(const short8*)(wb + 8192 + fo);   gg[nt] = MFMA(ax, b, gg[nt]);
      }
#pragma unroll
      for (int r = 0; r < 4; ++r) {
        float T0 = sigm(tp[0][r] + sigm(td[0][r]) + btr[0]);
        float T1 = sigm(tp[1][r] + sigm(td[1][r]) + btr[1]);
        float cs0 = sigm(gi[0][r] + bsir[0]) * T0 * tanh_(gg[0][r] + bsgr[0]);
        float cs1 = sigm(gi[1][r] + bsir[1]) * T1 * tanh_(gg[1][r] + bsgr[1]);
        float h0 = sigm(go[0][r] + bsor[0]) * tanh_(cs0);
        float h1 = sigm(go[1][r] + bsor[1]) * tanh_(cs1);
        int row = tm * 16 + quad * 4 + r;
        *(uint32_t*)(ldsT + row * 64 + l16 * 4) = pack2(T0, T1);
        *(uint32_t*)(pool + 16384 + row * 64 + l16 * 4) = pack2(h0, h1);
      }
    }
    __syncthreads();
    {
      int r = tid >> 1;
      int c0b = (tid & 1) * 32;
      uint8_t* dst = An + (size_t)(grow0 + r) * AROW + 512 + cb * 64 + c0b;
      *(short8*)dst = *(const short8*)(pool + 16384 + r * 64 + c0b);
      *(short8*)(dst + 16) = *(const short8*)(pool + 16384 + r * 64 + c0b + 16);
      if (cb == 0) {
        uint8_t* dx = An + (size_t)(grow0 + r) * AROW + 1024 + c0b;
        *(short8*)dx = *(const short8*)(pool + r * 64 + c0b);
        *(short8*)(dx + 16) = *(const short8*)(pool + r * 64 + c0b + 16);
      }
    }
  };

  /* per-row-group barrier: monotonic counter, agent scope */
  auto gbar = [&](uint32_t target) {
    __syncthreads();
    if (tid == 0) {
      __threadfence();
      __hip_atomic_fetch_add(cnt, 1u, __ATOMIC_RELEASE, __HIP_MEMORY_SCOPE_AGENT);
      while (__hip_atomic_load(cnt, __ATOMIC_ACQUIRE, __HIP_MEMORY_SCOPE_AGENT) < target)
        __builtin_amdgcn_s_sleep(2);
      __threadfence();
    }
    __syncthreads();
  };

  /* heads(ot): softmax(h@Wc+bc) and h@Wm+bm for this wg's 16 rows; f32 out.
     Uniform call; internal barrier between hsk write and cross-lane read. */
  auto heads = [&](int ot, const uint8_t* Ac) {
    float* hsk = (float*)pool;                        /* [16][33] floats */
    if (wv == 0) {
      floatx4 h0 = fz, h1 = fz;
      int hrow = grow0 + cb * 16;
#pragma unroll
      for (int s = 0; s < 8; ++s) {
        short8 a = *(const short8*)(Ac + (size_t)(hrow + l16) * AROW + s * 64 + quad * 16);
        short8 b0 = *(const short8*)(Wcm + (size_t)(l16 * 256 + s * 32 + quad * 8) * 2);
        short8 b1 = *(const short8*)(Wcm + (size_t)((16 + l16) * 256 + s * 32 + quad * 8) * 2);
        h0 = MFMA(a, b0, h0);
        h1 = MFMA(a, b1, h1);
      }
#pragma unroll
      for (int r = 0; r < 4; ++r) {
        hsk[(quad * 4 + r) * 33 + l16] = h0[r] + bcm[l16];
        hsk[(quad * 4 + r) * 33 + 16 + l16] = h1[r] + bcm[16 + l16];
      }
    }
    __syncthreads();
    if (wv == 0 && ln < 16) {
      int hrow = grow0 + cb * 16;
      float L0 = hsk[ln * 33 + 0], L1 = hsk[ln * 33 + 1], L2 = hsk[ln * 33 + 2];
      float mx = fmaxf(L0, fmaxf(L1, L2));
      float e0 = __expf(L0 - mx), e1 = __expf(L1 - mx), e2 = __expf(L2 - mx);
      float inv = 1.0f / (e0 + e1 + e2);
      size_t bi = (size_t)ot * BB + hrow + ln;
      float* oc = out_cat + bi * 3;
      oc[0] = e0 * inv; oc[1] = e1 * inv; oc[2] = e2 * inv;
      float* ov = out_val + bi * 22;
#pragma unroll
      for (int j = 0; j < 22; ++j) ov[j] = hsk[ln * 33 + 3 + j];
    }
  };

  extras(0, Abuf0);
  gbar(8u);

#pragma unroll 1
  for (int t = 0; t < SM1; ++t) {
    uint8_t* Ac = (t & 1) ? Abuf1 : Abuf0;
    uint8_t* An = (t & 1) ? Abuf0 : Abuf1;
    if (t > 0) heads(t - 1, Ac);   /* uniform condition; heads has internal barrier */
    __syncthreads();

    /* ---- main GEMM: pre_p[128 x 128] = A[128 x 544] * W ---- */
    floatx4 acc[8][2];
#pragma unroll
    for (int m = 0; m < 8; ++m) { acc[m][0] = fz; acc[m][1] = fz; }

    short8 st0, st1;
    {
      const uint8_t* src = Ac + (size_t)grow0 * AROW;
      st0 = *(const short8*)(src + (size_t)(tid >> 2) * AROW + (tid & 3) * 16);
      st1 = *(const short8*)(src + ((size_t)(tid >> 2) + 64) * AROW + (tid & 3) * 16);
      *(short8*)(pool + tid * 16) = st0;
      *(short8*)(pool + (tid + 256) * 16) = st1;
    }
    __syncthreads();

#pragma unroll
    for (int s = 0; s < NSL; ++s) {
      if (s < NSL - 1) {
        const uint8_t* src = Ac + (size_t)grow0 * AROW + (s + 1) * 64;
        st0 = *(const short8*)(src + (size_t)(tid >> 2) * AROW + (tid & 3) * 16);
        st1 = *(const short8*)(src + ((size_t)(tid >> 2) + 64) * AROW + (tid & 3) * 16);
      }
      const uint8_t* stg = pool + (s & 1) * 8192;
      short8 a[8];
#pragma unroll
      for (int m = 0; m < 8; ++m)
        a[m] = *(const short8*)(stg + (m * 16 + l16) * 64 + quad * 16);
#pragma unroll
      for (int m = 0; m < 8; ++m) {
        acc[m][0] = MFMA(a[m], Bf[s][0], acc[m][0]);
        acc[m][1] = MFMA(a[m], Bf[s][1], acc[m][1]);
      }
      if (s < NSL - 1) {
        uint8_t* dst = pool + ((s + 1) & 1) * 8192;
        *(short8*)(dst + tid * 16) = st0;
        *(short8*)(dst + (tid + 256) * 16) = st1;
      }
      __syncthreads();
    }

    /* ---- gate activations (wave wv = gate wv) -> exchange in pool ---- */
#pragma unroll
    for (int m = 0; m < 8; ++m) {
#pragma unroll
      for (int r = 0; r < 4; ++r) {
        float v0 = acc[m][0][r] + bpr[0];
        float v1 = acc[m][1][r] + bpr[1];
        float a0, a1;
        if (wv == 3) { a0 = tanh_(v0); a1 = tanh_(v1); }
        else { a0 = sigm(v0); a1 = sigm(v1); }
        int row = m * 16 + quad * 4 + r;
        *(uint32_t*)(pool + wv * 8192 + row * 64 + l16 * 4) = pack2(a0, a1);
      }
    }
    __syncthreads();

    /* ---- elementwise cell update; c-state in registers ---- */
    {
      int r = tid >> 1;
      int c0b = (tid & 1) * 32;
      const uint8_t* base = pool + r * 64 + c0b;
      short8 i0 = *(const short8*)(base);
      short8 i1 = *(const short8*)(base + 16);
      short8 f0 = *(const short8*)(base + 8192);
      short8 f1 = *(const short8*)(base + 8192 + 16);
      short8 o0 = *(const short8*)(base + 16384);
      short8 o1 = *(const short8*)(base + 16384 + 16);
      short8 g0 = *(const short8*)(base + 24576);
      short8 g1 = *(const short8*)(base + 24576 + 16);
      short8 T0 = *(const short8*)(ldsT + r * 64 + c0b);
      short8 T1 = *(const short8*)(ldsT + r * 64 + c0b + 16);
      short8 hA, hB;
#pragma unroll
      for (int jj = 0; jj < 16; ++jj) {
        float iv = b2f((uint16_t)(jj < 8 ? i0[jj] : i1[jj - 8]));
        float fv = b2f((uint16_t)(jj < 8 ? f0[jj] : f1[jj - 8]));
        float ov = b2f((uint16_t)(jj < 8 ? o0[jj] : o1[jj - 8]));
        float gv = b2f((uint16_t)(jj < 8 ? g0[jj] : g1[jj - 8]));
        float Tv = b2f((uint16_t)(jj < 8 ? T0[jj] : T1[jj - 8]));
        float cn = fv * c_reg[jj] + iv * Tv * gv;
        float hv = ov * tanh_(cn);
        c_reg[jj] = cn;
        uint16_t hb_ = f2b(hv);
        if (jj < 8) hA[jj] = (short)hb_; else hB[jj - 8] = (short)hb_;
      }
      uint8_t* dst = An + (size_t)(grow0 + r) * AROW + cb * 64 + c0b;
      *(short8*)dst = hA;
      *(short8*)(dst + 16) = hB;
    }
    __syncthreads();

    extras(t + 1, An);
    gbar(8u * (t + 2));
  }

  heads(SM1 - 1, Abuf1);
}

extern "C" void kernel_launch(void* const* d_in, const int* in_sizes, int n_in,
                              void* d_out, int out_size, void* d_ws, size_t ws_size,
                              hipStream_t stream) {
  (void)in_sizes; (void)n_in; (void)out_size; (void)ws_size;
  const float* val   = (const float*)d_in[1];
  const float* delta = (const float*)d_in[2];
  const float* Wd    = (const float*)d_in[3];
  const float* bd    = (const float*)d_in[4];
  const float* Wxt   = (const float*)d_in[5];
  const float* Wdt   = (const float*)d_in[6];
  const float* bt    = (const float*)d_in[7];
  const float* Wxs   = (const float*)d_in[8];
  const float* bs    = (const float*)d_in[10];
  const float* Wxp   = (const float*)d_in[11];
  const float* Whp   = (const float*)d_in[12];
  const float* Wsp   = (const float*)d_in[13];
  const float* bp    = (const float*)d_in[14];
  const float* Wc    = (const float*)d_in[15];
  const float* bc    = (const float*)d_in[16];
  const float* Wm    = (const float*)d_in[17];
  const float* bm    = (const float*)d_in[18];
  uint8_t* ws = (uint8_t*)d_ws;
  float* outp = (float*)d_out;

  hipMemsetAsync(d_ws, 0, WS_TOT, stream);
  prep_kernel<<<2208, 256, 0, stream>>>(Whp, Wsp, Wxp, Wc, Wm,
      (uint16_t*)(ws + WS_WT), (uint16_t*)(ws + WS_WCMT));
  scan_kernel<<<256, 256, 0, stream>>>(val, delta, Wd, bd, Wxt, Wdt, bt, Wxs,
      bs, bp, bc, bm, ws + WS_WT, ws + WS_WCMT, ws + WS_A0, ws + WS_A1,
      (uint32_t*)(ws + WS_CNT), outp);
}

// Round 4
// 8336.058 us; speedup vs baseline: 1.2896x; 1.2896x over previous
//
#include <hip/hip_runtime.h>
#include <stdint.h>
#include <stddef.h>

#define BB   4096
#define KTOT 544
#define AROW 1088            /* KTOT*2 bytes per A-matrix row */
#define NSL  17
#define SM1  255

/* workspace layout (bytes) */
#define WS_A0   0
#define WS_A1   4456448                   /* 4096*1088 */
#define WS_WT   8912896                   /* 2 A buffers */
#define WS_WCMT (WS_WT + 1114112)         /* 8*128*544*2 */
#define WS_CNT  (WS_WCMT + 16384)
#define WS_TOT  (WS_CNT + 8192)           /* 64 rb x 128B counters */

typedef __attribute__((ext_vector_type(8))) short short8;
typedef __attribute__((ext_vector_type(4))) float floatx4;

#define MFMA(a, b, c) __builtin_amdgcn_mfma_f32_16x16x32_bf16((a), (b), (c), 0, 0, 0)

static __device__ __forceinline__ uint16_t f2b(float f) {
  union { float f; uint32_t u; } v; v.f = f;
  return (uint16_t)((v.u + 0x7FFFu + ((v.u >> 16) & 1u)) >> 16);  /* RNE */
}
static __device__ __forceinline__ uint32_t pack2(float a, float b) {
  return (uint32_t)f2b(a) | ((uint32_t)f2b(b) << 16);
}
static __device__ __forceinline__ float b2f(uint16_t h) {
  union { uint32_t u; float f; } v; v.u = ((uint32_t)h) << 16; return v.f;
}
static __device__ __forceinline__ float sigm(float x) { return 1.0f / (1.0f + __expf(-x)); }
static __device__ __forceinline__ float tanh_(float x) {
  float a = fabsf(x);
  float e = __expf(-2.0f * a);
  float t = (1.0f - e) / (1.0f + e);
  return copysignf(t, x);
}

/* Repack combined weight [K=544][1024] (f32 in) -> bf16 B panels (unchanged layout).
   Head weights [Wc|Wm] -> bf16 [32 cols][256 k]. */
__global__ void prep_kernel(const float* __restrict__ Whp, const float* __restrict__ Wsp,
                            const float* __restrict__ Wxp, const float* __restrict__ Wc,
                            const float* __restrict__ Wm, uint16_t* __restrict__ Wt,
                            uint16_t* __restrict__ Wcmt) {
  int tid = blockIdx.x * 256 + threadIdx.x;
  const int NW = 8 * 128 * KTOT;
  if (tid < NW) {
    int k = tid % KTOT;
    int n = (tid / KTOT) & 127;
    int cb = tid / (KTOT * 128);
    int gate = n >> 5;
    int n5 = n & 31;
    int col = gate * 256 + cb * 32 + ((n5 & 15) << 1) + (n5 >> 4);
    float v = 0.0f;
    if (k < 256) v = Whp[k * 1024 + col];
    else if (k < 512) v = Wsp[(k - 256) * 1024 + col];
    else if (k < 532) v = Wxp[(k - 512) * 1024 + col];
    Wt[tid] = f2b(v);
  } else if (tid < NW + 8192) {
    int i2 = tid - NW;
    int k = i2 & 255;
    int n = i2 >> 8;
    float v = 0.0f;
    if (n < 3) v = Wc[k * 3 + n];
    else if (n < 25) v = Wm[k * 22 + (n - 3)];
    Wcmt[i2] = f2b(v);
  }
}

__global__ __launch_bounds__(256, 2) void scan_kernel(
    const float* __restrict__ val, const float* __restrict__ delta,
    const float* __restrict__ Wd, const float* __restrict__ bd,
    const float* __restrict__ Wxt, const float* __restrict__ Wdt,
    const float* __restrict__ bt, const float* __restrict__ Wxs,
    const float* __restrict__ bs, const float* __restrict__ bp,
    const float* __restrict__ bc, const float* __restrict__ bm,
    const uint8_t* __restrict__ Wt, const uint8_t* __restrict__ Wcm,
    uint8_t* __restrict__ Abuf0, uint8_t* __restrict__ Abuf1,
    uint32_t* __restrict__ counters, float* __restrict__ outp) {
  /* pool: extras staging x[0:4K)|demb[4K:8K)|hs1[8K:12K)  /  gates 4x4K (phases
     separated by barriers). */
  __shared__ __align__(16) uint8_t pool[16384];
  __shared__ __align__(16) uint8_t ldsT[4096];        /* T gate [64][32] bf16 */
  __shared__ __align__(16) uint16_t wext[5][1024];    /* Wdt | Wxt | Wxs_i | Wxs_o | Wxs_g */
  __shared__ float wdbd[64];                          /* W_d(32) | b_d(32) */
  __shared__ float bcm[32];                           /* bc(3) | bm(22) | 0 */

  const int tid = threadIdx.x;
  const int wv = tid >> 6;
  const int ln = tid & 63;
  const int quad = ln >> 4;
  const int l16 = ln & 15;
  /* siblings of a row group are blockIdx ≡ rb (mod 8) -> same XCD under
     round-robin dispatch (perf heuristic; correctness via agent scope). */
  const int rb = blockIdx.x & 63;   /* 64 row groups x 64 rows */
  const int cb = blockIdx.x >> 6;   /* 8 col chunks x 32 hcols */
  const int grow0 = rb * 64;
  uint32_t* cnt = counters + rb * 32;   /* 128B stride: no false sharing */
  float* out_cat = outp;
  float* out_val = outp + (size_t)SM1 * BB * 3;

  /* ---- startup: small weights into LDS (f32 -> bf16) ---- */
  {
    int n_e = tid >> 3;
    int k0 = (tid & 7) << 2;
    int colD = cb * 32 + ((n_e & 15) << 1) + (n_e >> 4);
#pragma unroll
    for (int j = 0; j < 4; ++j) {
      int k = k0 + j;
      wext[0][n_e * 32 + k] = f2b(Wdt[k * 256 + colD]);
      wext[1][n_e * 32 + k] = (k < 20) ? f2b(Wxt[k * 256 + colD]) : (uint16_t)0;
      wext[2][n_e * 32 + k] = (k < 20) ? f2b(Wxs[k * 1024 + colD]) : (uint16_t)0;
      wext[3][n_e * 32 + k] = (k < 20) ? f2b(Wxs[k * 1024 + 512 + colD]) : (uint16_t)0;
      wext[4][n_e * 32 + k] = (k < 20) ? f2b(Wxs[k * 1024 + 768 + colD]) : (uint16_t)0;
    }
    if (tid < 32) wdbd[tid] = Wd[tid];
    else if (tid < 64) wdbd[tid] = bd[tid - 32];
    if (tid >= 64 && tid < 96) {
      int n = tid - 64;
      bcm[n] = (n < 3) ? bc[n] : ((n < 25) ? bm[n - 3] : 0.0f);
    }
  }

  /* per-lane biases */
  float bpr[2], btr[2], bsir[2], bsor[2], bsgr[2];
#pragma unroll
  for (int nt = 0; nt < 2; ++nt) {
    int c = cb * 32 + l16 * 2 + nt;
    bpr[nt] = bp[wv * 256 + c];
    btr[nt] = bt[c];
    bsir[nt] = bs[c];
    bsor[nt] = bs[512 + c];
    bsgr[nt] = bs[768 + c];
  }

  /* main-GEMM B fragments: resident in VGPRs for all 255 steps */
  short8 Bf[NSL][2];
  {
    const uint8_t* wb = Wt + (size_t)cb * 128 * KTOT * 2;
#pragma unroll
    for (int s = 0; s < NSL; ++s)
#pragma unroll
      for (int nt = 0; nt < 2; ++nt) {
        int n = wv * 32 + nt * 16 + l16;
        Bf[s][nt] = *(const short8*)(wb + (size_t)n * AROW + s * 64 + quad * 16);
      }
  }

  float c_reg[8];
#pragma unroll
  for (int j = 0; j < 8; ++j) c_reg[j] = 0.0f;
  const floatx4 fz = {0.0f, 0.0f, 0.0f, 0.0f};

  __syncthreads();

  /* extras(u): stage x_u, demb_u; MFMA shared path + time gate; T->ldsT,
     hs1 (+x pad if cb==0) -> A buffer for step u. 64 rows. */
  auto extras = [&](int u, uint8_t* An) {
    {
      int r = tid >> 2, p = tid & 3;
      int grow = grow0 + r;
      uint32_t* xr = (uint32_t*)(pool + r * 64);
      uint32_t* dr = (uint32_t*)(pool + 4096 + r * 64);
      if (p < 2) {
        const float2* v2 = (const float2*)(val + ((size_t)u * BB + grow) * 20 + p * 10);
#pragma unroll
        for (int j = 0; j < 5; ++j) { float2 tv = v2[j]; xr[p * 5 + j] = pack2(tv.x, tv.y); }
        if (p == 1) {
#pragma unroll
          for (int j = 10; j < 16; ++j) xr[j] = 0u;
        }
      } else {
        float d = delta[(size_t)u * BB + grow];
        int e0 = (p - 2) * 16;
#pragma unroll
        for (int e = 0; e < 16; e += 2) {
          float d0 = tanh_(d * wdbd[e0 + e] + wdbd[32 + e0 + e]);
          float d1 = tanh_(d * wdbd[e0 + e + 1] + wdbd[32 + e0 + e + 1]);
          dr[(e0 + e) >> 1] = pack2(d0, d1);
        }
      }
    }
    __syncthreads();
    {
      int tm = wv;                     /* 4 m-tiles, one per wave */
      short8 ax = *(const short8*)(pool + (tm * 16 + l16) * 64 + quad * 16);
      short8 ad = *(const short8*)(pool + 4096 + (tm * 16 + l16) * 64 + quad * 16);
      floatx4 td[2], tp[2], gi[2], go[2], gg[2];
#pragma unroll
      for (int nt = 0; nt < 2; ++nt) {
        td[nt] = fz; tp[nt] = fz; gi[nt] = fz; go[nt] = fz; gg[nt] = fz;
        const uint8_t* wb = (const uint8_t*)wext;
        int fo = (nt * 16 + l16) * 64 + quad * 16;
        short8 b;
        b = *(const short8*)(wb + fo);          td[nt] = MFMA(ad, b, td[nt]);
        b = *(const short8*)(wb + 2048 + fo);   tp[nt] = MFMA(ax, b, tp[nt]);
        b = *(const short8*)(wb + 4096 + fo);   gi[nt] = MFMA(ax, b, gi[nt]);
        b = *(const short8*)(wb + 6144 + fo);   go[nt] = MFMA(ax, b, go[nt]);
        b = *(const short8*)(wb + 8192 + fo);   gg[nt] = MFMA(ax, b, gg[nt]);
      }
#pragma unroll
      for (int r = 0; r < 4; ++r) {
        float T0 = sigm(tp[0][r] + sigm(td[0][r]) + btr[0]);
        float T1 = sigm(tp[1][r] + sigm(td[1][r]) + btr[1]);
        float cs0 = sigm(gi[0][r] + bsir[0]) * T0 * tanh_(gg[0][r] + bsgr[0]);
        float cs1 = sigm(gi[1][r] + bsir[1]) * T1 * tanh_(gg[1][r] + bsgr[1]);
        float h0 = sigm(go[0][r] + bsor[0]) * tanh_(cs0);
        float h1 = sigm(go[1][r] + bsor[1]) * tanh_(cs1);
        int row = tm * 16 + quad * 4 + r;
        *(uint32_t*)(ldsT + row * 64 + l16 * 4) = pack2(T0, T1);
        *(uint32_t*)(pool + 8192 + row * 64 + l16 * 4) = pack2(h0, h1);
      }
    }
    __syncthreads();
    {
      int r = tid >> 2, p = tid & 3;
      uint8_t* dst = An + (size_t)(grow0 + r) * AROW + 512 + cb * 64 + p * 16;
      *(short8*)dst = *(const short8*)(pool + 8192 + r * 64 + p * 16);
      if (cb == 0) {
        uint8_t* dx = An + (size_t)(grow0 + r) * AROW + 1024 + p * 16;
        *(short8*)dx = *(const short8*)(pool + r * 64 + p * 16);
      }
    }
  };

  /* per-row-group barrier: release add, relaxed poll, one acquire fence */
  auto gbar = [&](uint32_t target) {
    __syncthreads();
    if (tid == 0) {
      __hip_atomic_fetch_add(cnt, 1u, __ATOMIC_RELEASE, __HIP_MEMORY_SCOPE_AGENT);
      while (__hip_atomic_load(cnt, __ATOMIC_RELAXED, __HIP_MEMORY_SCOPE_AGENT) < target)
        __builtin_amdgcn_s_sleep(1);
      __builtin_amdgcn_fence(__ATOMIC_ACQUIRE, "agent");
    }
    __syncthreads();
  };

  /* heads(ot): barrier-free (shfl transpose), done by wave hw only, cb<4.
     16 rows at hrow = grow0 + cb*16. */
  auto heads = [&](int ot, const uint8_t* Ac) {
    if (cb >= 4) return;
    int hw = ot & 3;
    if (wv != hw) return;
    floatx4 h0 = fz, h1 = fz;
    int hrow = grow0 + cb * 16;
#pragma unroll
    for (int s = 0; s < 8; ++s) {
      short8 a = *(const short8*)(Ac + (size_t)(hrow + l16) * AROW + s * 64 + quad * 16);
      short8 b0 = *(const short8*)(Wcm + (size_t)(l16 * 256 + s * 32 + quad * 8) * 2);
      short8 b1 = *(const short8*)(Wcm + (size_t)((16 + l16) * 256 + s * 32 + quad * 8) * 2);
      h0 = MFMA(a, b0, h0);
      h1 = MFMA(a, b1, h1);
    }
    float bc0 = bcm[0], bc1 = bcm[1], bc2 = bcm[2];
    float bcl = bcm[l16], bch = bcm[16 + l16];
#pragma unroll
    for (int r = 0; r < 4; ++r) {
      float L0 = __shfl(h0[r], quad * 16 + 0) + bc0;
      float L1 = __shfl(h0[r], quad * 16 + 1) + bc1;
      float L2 = __shfl(h0[r], quad * 16 + 2) + bc2;
      float mx = fmaxf(L0, fmaxf(L1, L2));
      float e0 = __expf(L0 - mx), e1 = __expf(L1 - mx), e2 = __expf(L2 - mx);
      float inv = 1.0f / (e0 + e1 + e2);
      size_t bi = (size_t)ot * BB + hrow + quad * 4 + r;
      if (l16 < 3) {
        float es = (l16 == 0) ? e0 : ((l16 == 1) ? e1 : e2);
        out_cat[bi * 3 + l16] = es * inv;
      } else {
        out_val[bi * 22 + (l16 - 3)] = h0[r] + bcl;
      }
      if (l16 < 9) out_val[bi * 22 + 13 + l16] = h1[r] + bch;
    }
  };

  extras(0, Abuf0);
  gbar(8u);

#pragma unroll 1
  for (int t = 0; t < SM1; ++t) {
    uint8_t* Ac = (t & 1) ? Abuf1 : Abuf0;
    uint8_t* An = (t & 1) ? Abuf0 : Abuf1;
    if (t > 0) heads(t - 1, Ac);   /* overlaps with other waves' GEMM */

    /* ---- main GEMM: pre_p[64 x 128] = A[64 x 544] * W; no barriers,
       direct global A-fragment reads, 2-deep manual pipeline + full unroll ---- */
    floatx4 acc[4][2];
#pragma unroll
    for (int m = 0; m < 4; ++m) { acc[m][0] = fz; acc[m][1] = fz; }

    const uint8_t* Ab = Ac + ((size_t)grow0 + l16) * AROW + quad * 16;
    short8 af[2][4];
#pragma unroll
    for (int m = 0; m < 4; ++m)
      af[0][m] = *(const short8*)(Ab + (size_t)m * 16 * AROW);
#pragma unroll
    for (int s = 0; s < NSL; ++s) {
      int cur = s & 1;
      if (s + 1 < NSL) {
#pragma unroll
        for (int m = 0; m < 4; ++m)
          af[cur ^ 1][m] = *(const short8*)(Ab + (size_t)m * 16 * AROW + (s + 1) * 64);
      }
#pragma unroll
      for (int m = 0; m < 4; ++m) {
        acc[m][0] = MFMA(af[cur][m], Bf[s][0], acc[m][0]);
        acc[m][1] = MFMA(af[cur][m], Bf[s][1], acc[m][1]);
      }
    }

    /* ---- gate activations (wave wv = gate wv) -> exchange in pool ---- */
#pragma unroll
    for (int m = 0; m < 4; ++m) {
#pragma unroll
      for (int r = 0; r < 4; ++r) {
        float v0 = acc[m][0][r] + bpr[0];
        float v1 = acc[m][1][r] + bpr[1];
        float a0, a1;
        if (wv == 3) { a0 = tanh_(v0); a1 = tanh_(v1); }
        else { a0 = sigm(v0); a1 = sigm(v1); }
        int row = m * 16 + quad * 4 + r;
        *(uint32_t*)(pool + wv * 4096 + row * 64 + l16 * 4) = pack2(a0, a1);
      }
    }
    __syncthreads();

    /* ---- elementwise cell update; c-state in registers ---- */
    {
      int r = tid >> 2, p = tid & 3;
      const uint8_t* base = pool + r * 64 + p * 16;
      short8 ig = *(const short8*)(base);
      short8 fg = *(const short8*)(base + 4096);
      short8 og = *(const short8*)(base + 8192);
      short8 gg = *(const short8*)(base + 12288);
      short8 Tg = *(const short8*)(ldsT + r * 64 + p * 16);
      short8 hv8;
#pragma unroll
      for (int jj = 0; jj < 8; ++jj) {
        float iv = b2f((uint16_t)ig[jj]);
        float fv = b2f((uint16_t)fg[jj]);
        float ov = b2f((uint16_t)og[jj]);
        float gv = b2f((uint16_t)gg[jj]);
        float Tv = b2f((uint16_t)Tg[jj]);
        float cn = fv * c_reg[jj] + iv * Tv * gv;
        float hv = ov * tanh_(cn);
        c_reg[jj] = cn;
        hv8[jj] = (short)f2b(hv);
      }
      uint8_t* dst = An + (size_t)(grow0 + r) * AROW + cb * 64 + p * 16;
      *(short8*)dst = hv8;
    }
    __syncthreads();

    extras(t + 1, An);
    gbar(8u * (t + 2));
  }

  heads(SM1 - 1, Abuf1);
}

extern "C" void kernel_launch(void* const* d_in, const int* in_sizes, int n_in,
                              void* d_out, int out_size, void* d_ws, size_t ws_size,
                              hipStream_t stream) {
  (void)in_sizes; (void)n_in; (void)out_size; (void)ws_size;
  const float* val   = (const float*)d_in[1];
  const float* delta = (const float*)d_in[2];
  const float* Wd    = (const float*)d_in[3];
  const float* bd    = (const float*)d_in[4];
  const float* Wxt   = (const float*)d_in[5];
  const float* Wdt   = (const float*)d_in[6];
  const float* bt    = (const float*)d_in[7];
  const float* Wxs   = (const float*)d_in[8];
  const float* bs    = (const float*)d_in[10];
  const float* Wxp   = (const float*)d_in[11];
  const float* Whp   = (const float*)d_in[12];
  const float* Wsp   = (const float*)d_in[13];
  const float* bp    = (const float*)d_in[14];
  const float* Wc    = (const float*)d_in[15];
  const float* bc    = (const float*)d_in[16];
  const float* Wm    = (const float*)d_in[17];
  const float* bm    = (const float*)d_in[18];
  uint8_t* ws = (uint8_t*)d_ws;
  float* outp = (float*)d_out;

  hipMemsetAsync(d_ws, 0, WS_TOT, stream);
  prep_kernel<<<2208, 256, 0, stream>>>(Whp, Wsp, Wxp, Wc, Wm,
      (uint16_t*)(ws + WS_WT), (uint16_t*)(ws + WS_WCMT));
  scan_kernel<<<512, 256, 0, stream>>>(val, delta, Wd, bd, Wxt, Wdt, bt, Wxs,
      bs, bp, bc, bm, ws + WS_WT, ws + WS_WCMT, ws + WS_A0, ws + WS_A1,
      (uint32_t*)(ws + WS_CNT), outp);
}

// Round 7
// 6309.424 us; speedup vs baseline: 1.7038x; 1.3212x over previous
//
#include <hip/hip_runtime.h>
#include <stdint.h>
#include <stddef.h>

#define BB   4096
#define KTOT 544
#define AROW 1088            /* KTOT*2 bytes per A-matrix row */
#define NSL  17
#define SM1  255

/* workspace layout (bytes) */
#define WS_A0   0
#define WS_A1   4456448                   /* 4096*1088 */
#define WS_WT   8912896                   /* 2 A buffers */
#define WS_WCMT (WS_WT + 1114112)         /* 8*128*544*2 */
#define WS_CNT  (WS_WCMT + 16384)
#define WS_TOT  (WS_CNT + 8192)           /* 64 rb x 128B counters */

typedef __attribute__((ext_vector_type(8))) short short8;
typedef __attribute__((ext_vector_type(4))) float floatx4;

#define MFMA(a, b, c) __builtin_amdgcn_mfma_f32_16x16x32_bf16((a), (b), (c), 0, 0, 0)

/* Device-coherent 16B store/load: text-asm sc0 sc1 (the gfx950 CPol spelling
   we can trust, vs the builtin aux bits which R5/R6 show were NOT coherent).
   Writes go through to the coherence point; reads probe past L1/L2. */
static __device__ __forceinline__ void llc_st16(void* p, short8 v) {
  asm volatile("global_store_dwordx4 %0, %1, off sc0 sc1" :: "v"(p), "v"(v) : "memory");
}
static __device__ __forceinline__ short8 llc_ld16(const void* p) {
  short8 r;
  asm volatile("global_load_dwordx4 %0, %1, off sc0 sc1" : "=&v"(r) : "v"(p) : "memory");
  return r;   /* NOT ready until an explicit s_waitcnt vmcnt retires it! */
}
#define WAITV(n) asm volatile("s_waitcnt vmcnt(" #n ")" ::: "memory")

static __device__ __forceinline__ uint16_t f2b(float f) {
  union { float f; uint32_t u; } v; v.f = f;
  return (uint16_t)((v.u + 0x7FFFu + ((v.u >> 16) & 1u)) >> 16);  /* RNE */
}
static __device__ __forceinline__ uint32_t pack2(float a, float b) {
  return (uint32_t)f2b(a) | ((uint32_t)f2b(b) << 16);
}
static __device__ __forceinline__ float b2f(uint16_t h) {
  union { uint32_t u; float f; } v; v.u = ((uint32_t)h) << 16; return v.f;
}
static __device__ __forceinline__ float sigm(float x) { return 1.0f / (1.0f + __expf(-x)); }
static __device__ __forceinline__ float tanh_(float x) {
  float a = fabsf(x);
  float e = __expf(-2.0f * a);
  float t = (1.0f - e) / (1.0f + e);
  return copysignf(t, x);
}

/* Repack combined weight [K=544][1024] (f32 in) -> bf16 B panels.
   Head weights [Wc|Wm] -> bf16 [32 cols][256 k]. */
__global__ void prep_kernel(const float* __restrict__ Whp, const float* __restrict__ Wsp,
                            const float* __restrict__ Wxp, const float* __restrict__ Wc,
                            const float* __restrict__ Wm, uint16_t* __restrict__ Wt,
                            uint16_t* __restrict__ Wcmt) {
  int tid = blockIdx.x * 256 + threadIdx.x;
  const int NW = 8 * 128 * KTOT;
  if (tid < NW) {
    int k = tid % KTOT;
    int n = (tid / KTOT) & 127;
    int cb = tid / (KTOT * 128);
    int gate = n >> 5;
    int n5 = n & 31;
    int col = gate * 256 + cb * 32 + ((n5 & 15) << 1) + (n5 >> 4);
    float v = 0.0f;
    if (k < 256) v = Whp[k * 1024 + col];
    else if (k < 512) v = Wsp[(k - 256) * 1024 + col];
    else if (k < 532) v = Wxp[(k - 512) * 1024 + col];
    Wt[tid] = f2b(v);
  } else if (tid < NW + 8192) {
    int i2 = tid - NW;
    int k = i2 & 255;
    int n = i2 >> 8;
    float v = 0.0f;
    if (n < 3) v = Wc[k * 3 + n];
    else if (n < 25) v = Wm[k * 22 + (n - 3)];
    Wcmt[i2] = f2b(v);
  }
}

__global__ __launch_bounds__(256, 2) void scan_kernel(
    const float* __restrict__ val, const float* __restrict__ delta,
    const float* __restrict__ Wd, const float* __restrict__ bd,
    const float* __restrict__ Wxt, const float* __restrict__ Wdt,
    const float* __restrict__ bt, const float* __restrict__ Wxs,
    const float* __restrict__ bs, const float* __restrict__ bp,
    const float* __restrict__ bc, const float* __restrict__ bm,
    const uint8_t* __restrict__ Wt, const uint8_t* __restrict__ Wcm,
    uint8_t* __restrict__ Abuf0, uint8_t* __restrict__ Abuf1,
    uint32_t* __restrict__ counters, float* __restrict__ outp) {
  /* arena phases (barrier-separated):
     gates: 4 waves x 5120B (stride-80 rows) [0..20480)
     extras: x[0..4K) | demb[4K..8K) | hs1[8K..12K) */
  __shared__ __align__(16) uint8_t arena[20480];
  __shared__ __align__(16) uint8_t ldsT[4096];        /* T gate [64][32] bf16 */
  __shared__ __align__(16) uint16_t wext[5][1024];    /* Wdt | Wxt | Wxs_i | Wxs_o | Wxs_g */
  __shared__ float wdbd[64];                          /* W_d(32) | b_d(32) */
  __shared__ float bcm[32];                           /* bc(3) | bm(22) | 0 */

  const int tid = threadIdx.x;
  const int wv = tid >> 6;
  const int ln = tid & 63;
  const int quad = ln >> 4;
  const int l16 = ln & 15;
  const int rb = blockIdx.x & 63;   /* 64 row groups x 64 rows */
  const int cb = blockIdx.x >> 6;   /* 8 col chunks x 32 hcols */
  const int grow0 = rb * 64;
  uint32_t* cnt = counters + rb * 32;   /* 128B stride */
  float* out_cat = outp;
  float* out_val = outp + (size_t)SM1 * BB * 3;

  /* ---- startup: small weights into LDS (f32 -> bf16) ---- */
  {
    int n_e = tid >> 3;
    int k0 = (tid & 7) << 2;
    int colD = cb * 32 + ((n_e & 15) << 1) + (n_e >> 4);
#pragma unroll
    for (int j = 0; j < 4; ++j) {
      int k = k0 + j;
      wext[0][n_e * 32 + k] = f2b(Wdt[k * 256 + colD]);
      wext[1][n_e * 32 + k] = (k < 20) ? f2b(Wxt[k * 256 + colD]) : (uint16_t)0;
      wext[2][n_e * 32 + k] = (k < 20) ? f2b(Wxs[k * 1024 + colD]) : (uint16_t)0;
      wext[3][n_e * 32 + k] = (k < 20) ? f2b(Wxs[k * 1024 + 512 + colD]) : (uint16_t)0;
      wext[4][n_e * 32 + k] = (k < 20) ? f2b(Wxs[k * 1024 + 768 + colD]) : (uint16_t)0;
    }
    if (tid < 32) wdbd[tid] = Wd[tid];
    else if (tid < 64) wdbd[tid] = bd[tid - 32];
    if (tid >= 64 && tid < 96) {
      int n = tid - 64;
      bcm[n] = (n < 3) ? bc[n] : ((n < 25) ? bm[n - 3] : 0.0f);
    }
  }

  float bpr[2], btr[2], bsir[2], bsor[2], bsgr[2];
#pragma unroll
  for (int nt = 0; nt < 2; ++nt) {
    int c = cb * 32 + l16 * 2 + nt;
    bpr[nt] = bp[wv * 256 + c];
    btr[nt] = bt[c];
    bsir[nt] = bs[c];
    bsor[nt] = bs[512 + c];
    bsgr[nt] = bs[768 + c];
  }

  /* main-GEMM B fragments (compiler may cache or re-load from L2 — Wt is
     read-only after prep, so normal cached loads are safe) */
  const uint8_t* wbase = Wt + (size_t)cb * 128 * KTOT * 2;

  float c_reg[8];
#pragma unroll
  for (int j = 0; j < 8; ++j) c_reg[j] = 0.0f;
  const floatx4 fz = {0.0f, 0.0f, 0.0f, 0.0f};

  __syncthreads();

  /* extras(u): stage x_u, demb_u; MFMA shared path + time gate; T->ldsT,
     hs1 (+x pad if cb==0) -> A buffer (coherent stores). */
  auto extras = [&](int u, uint8_t* An) {
    {
      int r = tid >> 2, p = tid & 3;
      int grow = grow0 + r;
      uint32_t* xr = (uint32_t*)(arena + r * 64);
      uint32_t* dr = (uint32_t*)(arena + 4096 + r * 64);
      if (p < 2) {
        const float2* v2 = (const float2*)(val + ((size_t)u * BB + grow) * 20 + p * 10);
#pragma unroll
        for (int j = 0; j < 5; ++j) { float2 tv = v2[j]; xr[p * 5 + j] = pack2(tv.x, tv.y); }
        if (p == 1) {
#pragma unroll
          for (int j = 10; j < 16; ++j) xr[j] = 0u;
        }
      } else {
        float d = delta[(size_t)u * BB + grow];
        int e0 = (p - 2) * 16;
#pragma unroll
        for (int e = 0; e < 16; e += 2) {
          float d0 = tanh_(d * wdbd[e0 + e] + wdbd[32 + e0 + e]);
          float d1 = tanh_(d * wdbd[e0 + e + 1] + wdbd[32 + e0 + e + 1]);
          dr[(e0 + e) >> 1] = pack2(d0, d1);
        }
      }
    }
    __syncthreads();
    {
      int tm = wv;
      short8 ax = *(const short8*)(arena + (tm * 16 + l16) * 64 + quad * 16);
      short8 ad = *(const short8*)(arena + 4096 + (tm * 16 + l16) * 64 + quad * 16);
      floatx4 td[2], tp[2], gi[2], go[2], gg[2];
#pragma unroll
      for (int nt = 0; nt < 2; ++nt) {
        td[nt] = fz; tp[nt] = fz; gi[nt] = fz; go[nt] = fz; gg[nt] = fz;
        const uint8_t* wb = (const uint8_t*)wext;
        int fo = (nt * 16 + l16) * 64 + quad * 16;
        short8 b;
        b = *(const short8*)(wb + fo);          td[nt] = MFMA(ad, b, td[nt]);
        b = *(const short8*)(wb + 2048 + fo);   tp[nt] = MFMA(ax, b, tp[nt]);
        b = *(const short8*)(wb + 4096 + fo);   gi[nt] = MFMA(ax, b, gi[nt]);
        b = *(const short8*)(wb + 6144 + fo);   go[nt] = MFMA(ax, b, go[nt]);
        b = *(const short8*)(wb + 8192 + fo);   gg[nt] = MFMA(ax, b, gg[nt]);
      }
#pragma unroll
      for (int r = 0; r < 4; ++r) {
        float T0 = sigm(tp[0][r] + sigm(td[0][r]) + btr[0]);
        float T1 = sigm(tp[1][r] + sigm(td[1][r]) + btr[1]);
        float cs0 = sigm(gi[0][r] + bsir[0]) * T0 * tanh_(gg[0][r] + bsgr[0]);
        float cs1 = sigm(gi[1][r] + bsir[1]) * T1 * tanh_(gg[1][r] + bsgr[1]);
        float h0 = sigm(go[0][r] + bsor[0]) * tanh_(cs0);
        float h1 = sigm(go[1][r] + bsor[1]) * tanh_(cs1);
        int row = tm * 16 + quad * 4 + r;
        *(uint32_t*)(ldsT + row * 64 + l16 * 4) = pack2(T0, T1);
        *(uint32_t*)(arena + 8192 + row * 64 + l16 * 4) = pack2(h0, h1);
      }
    }
    __syncthreads();
    {
      int r = tid >> 2, p = tid & 3;
      short8 h8 = *(const short8*)(arena + 8192 + r * 64 + p * 16);
      llc_st16(An + (size_t)(grow0 + r) * AROW + 512 + cb * 64 + p * 16, h8);
      if (cb == 0) {
        short8 x8 = *(const short8*)(arena + r * 64 + p * 16);
        llc_st16(An + (size_t)(grow0 + r) * AROW + 1024 + p * 16, x8);
      }
    }
  };

  /* per-row-group barrier: ALL relaxed (never emits wbl2/inv). Visibility via
     coherent stores/loads; ordering via explicit vmcnt(0) + barrier. */
  auto gbar = [&](uint32_t target) {
    WAITV(0);
    __syncthreads();
    if (tid == 0) {
      __hip_atomic_fetch_add(cnt, 1u, __ATOMIC_RELAXED, __HIP_MEMORY_SCOPE_AGENT);
      while (__hip_atomic_load(cnt, __ATOMIC_RELAXED, __HIP_MEMORY_SCOPE_AGENT) < target)
        __builtin_amdgcn_s_sleep(1);
    }
    __syncthreads();
  };

  /* heads(ot): 8 coherent loads of 16 h-rows + MFMA + softmax; one wave
     (rotating), no block barriers. R4 addressing (known-good). */
  auto heads = [&](int ot, const uint8_t* Ac) {
    int hrow = grow0 + cb * 16;
    const uint8_t* g = Ac + (size_t)(hrow + l16) * AROW + quad * 16;
    short8 ha[8];
#pragma unroll
    for (int s = 0; s < 8; ++s) ha[s] = llc_ld16(g + s * 64);
    WAITV(0);
    floatx4 h0 = fz, h1 = fz;
#pragma unroll
    for (int s = 0; s < 8; ++s) {
      short8 b0 = *(const short8*)(Wcm + (size_t)(l16 * 256 + s * 32 + quad * 8) * 2);
      short8 b1 = *(const short8*)(Wcm + (size_t)((16 + l16) * 256 + s * 32 + quad * 8) * 2);
      h0 = MFMA(ha[s], b0, h0);
      h1 = MFMA(ha[s], b1, h1);
    }
    float bc0 = bcm[0], bc1 = bcm[1], bc2 = bcm[2];
    float bcl = bcm[l16], bch = bcm[16 + l16];
#pragma unroll
    for (int r = 0; r < 4; ++r) {
      float L0 = __shfl(h0[r], quad * 16 + 0) + bc0;
      float L1 = __shfl(h0[r], quad * 16 + 1) + bc1;
      float L2 = __shfl(h0[r], quad * 16 + 2) + bc2;
      float mx = fmaxf(L0, fmaxf(L1, L2));
      float e0 = __expf(L0 - mx), e1 = __expf(L1 - mx), e2 = __expf(L2 - mx);
      float inv = 1.0f / (e0 + e1 + e2);
      size_t bi = (size_t)ot * BB + hrow + quad * 4 + r;
      if (l16 < 3) {
        float es = (l16 == 0) ? e0 : ((l16 == 1) ? e1 : e2);
        out_cat[bi * 3 + l16] = es * inv;
      } else {
        out_val[bi * 22 + (l16 - 3)] = h0[r] + bcl;
      }
      if (l16 < 9) out_val[bi * 22 + 13 + l16] = h1[r] + bch;
    }
  };

  extras(0, Abuf0);
  gbar(8u);

#pragma unroll 1
  for (int t = 0; t < SM1; ++t) {
    const uint8_t* Ac = (t & 1) ? Abuf1 : Abuf0;
    uint8_t* An = (t & 1) ? Abuf0 : Abuf1;
    if ((t > 0) && (cb < 4) && (wv == ((t - 1) & 3))) heads(t - 1, Ac);

    /* ---- main GEMM: pre_p[64 x 128] = A[64 x 544] * W; coherent direct
       loads (R4 addressing), 2-slice manual pipeline. vmcnt(4) is always
       safe: vmcnt retires in order, so "all but newest 4" includes the
       current slice's 4 loads regardless of compiler-inserted vmem. ---- */
    floatx4 acc[4][2];
#pragma unroll
    for (int m = 0; m < 4; ++m) { acc[m][0] = fz; acc[m][1] = fz; }

    const uint8_t* Ab = Ac + ((size_t)grow0 + l16) * AROW + quad * 16;
    short8 af[2][4];
#pragma unroll
    for (int m = 0; m < 4; ++m)
      af[0][m] = llc_ld16(Ab + (size_t)m * 16 * AROW);
#pragma unroll
    for (int s = 0; s < NSL; ++s) {
      int cur = s & 1;
      if (s + 1 < NSL) {
#pragma unroll
        for (int m = 0; m < 4; ++m)
          af[cur ^ 1][m] = llc_ld16(Ab + (size_t)m * 16 * AROW + (s + 1) * 64);
        WAITV(4);
      } else {
        WAITV(0);
      }
      short8 b0 = *(const short8*)(wbase + (size_t)(wv * 32 + l16) * AROW + s * 64 + quad * 16);
      short8 b1 = *(const short8*)(wbase + (size_t)(wv * 32 + 16 + l16) * AROW + s * 64 + quad * 16);
#pragma unroll
      for (int m = 0; m < 4; ++m) {
        acc[m][0] = MFMA(af[cur][m], b0, acc[m][0]);
        acc[m][1] = MFMA(af[cur][m], b1, acc[m][1]);
      }
    }

    /* ---- gate activations -> exchange (stride-80 rows) ---- */
#pragma unroll
    for (int m = 0; m < 4; ++m) {
#pragma unroll
      for (int r = 0; r < 4; ++r) {
        float v0 = acc[m][0][r] + bpr[0];
        float v1 = acc[m][1][r] + bpr[1];
        float a0, a1;
        if (wv == 3) { a0 = tanh_(v0); a1 = tanh_(v1); }
        else { a0 = sigm(v0); a1 = sigm(v1); }
        int row = m * 16 + quad * 4 + r;
        *(uint32_t*)(arena + wv * 5120 + row * 80 + l16 * 4) = pack2(a0, a1);
      }
    }
    __syncthreads();

    /* ---- elementwise cell update; c-state in registers; h -> LLC ---- */
    {
      int r = tid >> 2, p = tid & 3;
      const uint8_t* gb = arena + r * 80 + p * 16;
      short8 ig = *(const short8*)(gb);
      short8 fg = *(const short8*)(gb + 5120);
      short8 og = *(const short8*)(gb + 10240);
      short8 gg8 = *(const short8*)(gb + 15360);
      short8 Tg = *(const short8*)(ldsT + r * 64 + p * 16);
      short8 hv8;
#pragma unroll
      for (int jj = 0; jj < 8; ++jj) {
        float iv = b2f((uint16_t)ig[jj]);
        float fv = b2f((uint16_t)fg[jj]);
        float ov = b2f((uint16_t)og[jj]);
        float gv = b2f((uint16_t)gg8[jj]);
        float Tv = b2f((uint16_t)Tg[jj]);
        float cn = fv * c_reg[jj] + iv * Tv * gv;
        float hv = ov * tanh_(cn);
        c_reg[jj] = cn;
        hv8[jj] = (short)f2b(hv);
      }
      llc_st16(An + (size_t)(grow0 + r) * AROW + cb * 64 + p * 16, hv8);
    }
    __syncthreads();   /* arena/ldsT free for extras */

    if (t + 1 < SM1) extras(t + 1, An);
    gbar(8u * (t + 2));
  }

  if (cb < 4 && wv == ((SM1 - 1) & 3)) heads(SM1 - 1, Abuf1);
}

extern "C" void kernel_launch(void* const* d_in, const int* in_sizes, int n_in,
                              void* d_out, int out_size, void* d_ws, size_t ws_size,
                              hipStream_t stream) {
  (void)in_sizes; (void)n_in; (void)out_size; (void)ws_size;
  const float* val   = (const float*)d_in[1];
  const float* delta = (const float*)d_in[2];
  const float* Wd    = (const float*)d_in[3];
  const float* bd    = (const float*)d_in[4];
  const float* Wxt   = (const float*)d_in[5];
  const float* Wdt   = (const float*)d_in[6];
  const float* bt    = (const float*)d_in[7];
  const float* Wxs   = (const float*)d_in[8];
  const float* bs    = (const float*)d_in[10];
  const float* Wxp   = (const float*)d_in[11];
  const float* Whp   = (const float*)d_in[12];
  const float* Wsp   = (const float*)d_in[13];
  const float* bp    = (const float*)d_in[14];
  const float* Wc    = (const float*)d_in[15];
  const float* bc    = (const float*)d_in[16];
  const float* Wm    = (const float*)d_in[17];
  const float* bm    = (const float*)d_in[18];
  uint8_t* ws = (uint8_t*)d_ws;
  float* outp = (float*)d_out;

  hipMemsetAsync(d_ws, 0, WS_TOT, stream);
  prep_kernel<<<2208, 256, 0, stream>>>(Whp, Wsp, Wxp, Wc, Wm,
      (uint16_t*)(ws + WS_WT), (uint16_t*)(ws + WS_WCMT));
  scan_kernel<<<512, 256, 0, stream>>>(val, delta, Wd, bd, Wxt, Wdt, bt, Wxs,
      bs, bp, bc, bm, ws + WS_WT, ws + WS_WCMT, ws + WS_A0, ws + WS_A1,
      (uint32_t*)(ws + WS_CNT), outp);
}